// Round 2
// baseline (75.287 us; speedup 1.0000x reference)
//
#include <hip/hip_runtime.h>
#include <math.h>

#define LOG2E 1.4426950408889634f
#define LN2   0.6931471805599453f

static constexpr int M = 1024;
static constexpr int N = 65536;

typedef float v2f  __attribute__((ext_vector_type(2)));
typedef float v8f  __attribute__((ext_vector_type(8)));
typedef float v16f __attribute__((ext_vector_type(16)));

__device__ inline float wave_max64(float v) {
    #pragma unroll
    for (int o = 32; o > 0; o >>= 1) v = fmaxf(v, __shfl_xor(v, o));
    return v;
}
__device__ inline float wave_sum64(float v) {
    #pragma unroll
    for (int o = 32; o > 0; o >>= 1) v += __shfl_xor(v, o);
    return v;
}

// d = cs * f + prev (packed f32). cs is wave-uniform, fed from an SGPR pair:
// exactly one scalar operand per VALU instruction (legal on VOP3P).
__device__ inline v2f pkfma(v2f cs, v2f f, v2f prev) {
    v2f d;
    asm("v_pk_fma_f32 %0, %1, %2, %3" : "=v"(d) : "s"(cs), "v"(f), "v"(prev));
    return d;
}

// ---------------- prep: 1 block x 1024 threads (tiny) ----------------
// Coef table (pair-interleaved, NOT duplicated): comp j -> pair p=j>>1,
// sub=j&1: ws[p*12 + 2*c + sub], c=0..5.
// No maxt2 needed: v = t2 - LOG2E*q <= t2 ~ 8.2, exp2 cannot overflow.
// ws[M*6] = -lse2  (the only cross-component scalar, used in main epilogue).
__global__ __launch_bounds__(1024)
void gm_prep(const float* __restrict__ mu,
             const float* __restrict__ A,
             const float* __restrict__ w,
             float* __restrict__ ws) {
    __shared__ float redA[16];
    const int t    = threadIdx.x;
    const int lane = t & 63;
    const int wv   = t >> 6;

    const float4 a = ((const float4*)A)[t];       // A00,A01,A10,A11
    const float g00 = a.x*a.x + a.y*a.y;
    const float g01 = a.x*a.z + a.y*a.w;
    const float g11 = a.z*a.z + a.w*a.w;
    const float2 m  = ((const float2*)mu)[t];
    const float gm0 = g00*m.x + g01*m.y;
    const float gm1 = g01*m.x + g11*m.y;
    const float mGm = gm0*m.x + gm1*m.y;
    const float det = g00*g11 - g01*g01;

    const float w2 = w[t] * LOG2E;
    const float t2 = w2 + 0.5f * __builtin_amdgcn_logf(det);

    {   // coefficient table (no reduction dependency)
        float* c = ws + (t >> 1)*12 + (t & 1);
        c[0]  = t2 - LOG2E * mGm;
        c[2]  = LOG2E * 2.0f * gm0;
        c[4]  = LOG2E * 2.0f * gm1;
        c[6]  = -LOG2E * g00;
        c[8]  = -LOG2E * 2.0f * g01;
        c[10] = -LOG2E * g11;
    }

    // -lse2 over w (stable form)
    float mw = wave_max64(w2);
    if (lane == 0) redA[wv] = mw;
    __syncthreads();
    float wmax2 = redA[0];
    #pragma unroll
    for (int i = 1; i < 16; i++) wmax2 = fmaxf(wmax2, redA[i]);
    __syncthreads();                    // protect redA before reuse
    const float sw = wave_sum64(__builtin_amdgcn_exp2f(w2 - wmax2));
    if (lane == 0) redA[wv] = sw;
    __syncthreads();
    if (t == 0) {
        float se = 0.0f;
        #pragma unroll
        for (int i = 0; i < 16; i++) se += redA[i];
        ws[M*6] = -(wmax2 + __builtin_amdgcn_logf(se));
    }
}

// ---------------- main: 256 blocks x 1024 threads ----------------
// Block: 256 samples, S=4 per lane. Wave wv owns comps [wv*64, wv*64+64),
// processed as 16 batches of 4 comps (2 pairs, 24 dwords of coefs).
// Coefs stream through the SCALAR pipe (s_load_dwordx16/x8 -> SGPRs),
// double-buffered; inner loop has ZERO LDS/VMEM instructions.
__global__ __launch_bounds__(1024)
void gm_main(const float* __restrict__ sample,
             const float* __restrict__ ws,
             float* __restrict__ out) {
    __shared__ float partial[16*256];             // 16 KiB
    const int t    = threadIdx.x;
    const int lane = t & 63;
    const int wv   = t >> 6;
    const int base = blockIdx.x * 256;

    float xv[4], yv[4];
    #pragma unroll
    for (int k = 0; k < 4; ++k) {
        const float2 p = ((const float2*)sample)[base + 64*k + lane];
        xv[k] = p.x; yv[k] = p.y;
    }

    // wave-uniform coef base in SGPRs
    const int wvu = __builtin_amdgcn_readfirstlane(wv);
    const float* cb = ws + wvu * (64*6);          // 1536 B per wave slice

    v2f X[4], Y[4], XX[4], XY[4], YY[4];
    #pragma unroll
    for (int k = 0; k < 4; ++k) {
        X[k]  = (v2f){xv[k], xv[k]};
        Y[k]  = (v2f){yv[k], yv[k]};
        XX[k] = (v2f){xv[k]*xv[k], xv[k]*xv[k]};
        XY[k] = (v2f){xv[k]*yv[k], xv[k]*yv[k]};
        YY[k] = (v2f){yv[k]*yv[k], yv[k]*yv[k]};
    }

    float acc[4] = {0.0f, 0.0f, 0.0f, 0.0f};

    v16f qA[2]; v8f qB[2];
    // prologue: issue batch 0
    asm volatile("s_load_dwordx16 %0, %1, 0"  : "=s"(qA[0]) : "s"(cb));
    asm volatile("s_load_dwordx8  %0, %1, 64" : "=s"(qB[0]) : "s"(cb));

    #pragma unroll
    for (int b = 0; b < 16; ++b) {
        // SMEM returns out of order -> only lgkmcnt(0) is safe; prefetch of
        // b+1 is issued AFTER this wait so its latency hides under compute b.
        asm volatile("s_waitcnt lgkmcnt(0)");
        __builtin_amdgcn_sched_barrier(0);        // rule 18: pin uses after wait
        if (b < 15) {
            asm volatile("s_load_dwordx16 %0, %1, %2"
                         : "=s"(qA[(b+1)&1]) : "s"(cb), "i"((b+1)*96));
            asm volatile("s_load_dwordx8  %0, %1, %2"
                         : "=s"(qB[(b+1)&1]) : "s"(cb), "i"((b+1)*96 + 64));
        }
        const v16f qa = qA[b&1];
        const v8f  qb = qB[b&1];
        // pair a: qa[0..11]; pair b: qa[12..15] + qb[0..7] (all even-aligned)
        const v2f c0a = {qa[0],  qa[1]},  c1a = {qa[2],  qa[3]};
        const v2f c2a = {qa[4],  qa[5]},  c3a = {qa[6],  qa[7]};
        const v2f c4a = {qa[8],  qa[9]},  c5a = {qa[10], qa[11]};
        const v2f c0b = {qa[12], qa[13]}, c1b = {qa[14], qa[15]};
        const v2f c2b = {qb[0],  qb[1]},  c3b = {qb[2],  qb[3]};
        const v2f c4b = {qb[4],  qb[5]},  c5b = {qb[6],  qb[7]};

        #pragma unroll
        for (int k = 0; k < 4; ++k) {
            v2f va = pkfma(c1a, X[k], c0a);       // c0a: auto s->v copy, CSE'd
            va = pkfma(c2a, Y[k],  va);
            va = pkfma(c3a, XX[k], va);
            va = pkfma(c4a, XY[k], va);
            va = pkfma(c5a, YY[k], va);
            v2f vb = pkfma(c1b, X[k], c0b);
            vb = pkfma(c2b, Y[k],  vb);
            vb = pkfma(c3b, XX[k], vb);
            vb = pkfma(c4b, XY[k], vb);
            vb = pkfma(c5b, YY[k], vb);
            acc[k] += (__builtin_amdgcn_exp2f(va.x) + __builtin_amdgcn_exp2f(va.y))
                    + (__builtin_amdgcn_exp2f(vb.x) + __builtin_amdgcn_exp2f(vb.y));
        }
    }

    #pragma unroll
    for (int k = 0; k < 4; ++k)
        partial[wv*256 + 64*k + lane] = acc[k];
    __syncthreads();

    if (t < 256) {
        float s = partial[t];
        #pragma unroll
        for (int i = 1; i < 16; ++i) s += partial[i*256 + t];
        const float nlse = ws[M*6];               // = -lse2
        out[base + t] = LN2 * (nlse + __builtin_amdgcn_logf(s));
    }
}

extern "C" void kernel_launch(void* const* d_in, const int* in_sizes, int n_in,
                              void* d_out, int out_size, void* d_ws, size_t ws_size,
                              hipStream_t stream) {
    const float* sample = (const float*)d_in[0];
    const float* mu     = (const float*)d_in[1];
    const float* A      = (const float*)d_in[2];
    const float* w      = (const float*)d_in[3];
    (void)in_sizes; (void)n_in; (void)out_size; (void)ws_size;

    gm_prep<<<1, 1024, 0, stream>>>(mu, A, w, (float*)d_ws);
    gm_main<<<N/256, 1024, 0, stream>>>(sample, (const float*)d_ws, (float*)d_out);
}

// Round 4
// 74.037 us; speedup vs baseline: 1.0169x; 1.0169x over previous
//
#include <hip/hip_runtime.h>
#include <math.h>

#define LOG2E 1.4426950408889634f
#define LN2   0.6931471805599453f

static constexpr int M = 1024;
static constexpr int N = 65536;

typedef float v2f __attribute__((ext_vector_type(2)));

// packed f32 fma (VOP3P, gfx90a+/gfx950): d = a*b + c on both 32-bit halves
__device__ inline v2f pkfma(v2f a, v2f b, v2f c) {
    v2f d;
    asm("v_pk_fma_f32 %0, %1, %2, %3" : "=v"(d) : "v"(a), "v"(b), "v"(c));
    return d;
}

__device__ inline float wave_max64(float v) {
    #pragma unroll
    for (int o = 32; o > 0; o >>= 1) v = fmaxf(v, __shfl_xor(v, o));
    return v;
}
__device__ inline float wave_sum64(float v) {
    #pragma unroll
    for (int o = 32; o > 0; o >>= 1) v += __shfl_xor(v, o);
    return v;
}

// Single kernel: 256 blocks x 1024 threads (1 block/CU, 4 waves/SIMD).
// Per block: 256 samples (4/lane). Wave wv owns comps [wv*64, wv*64+64).
// NO block barrier before the main loop:
//   - each wave computes coefs for ITS 64 comps and ds_writes its private
//     LDS slice; same-wave DS ops are in-order, so lgkmcnt(0) suffices.
//   - each wave redundantly computes the w-logsumexp from global memory.
// exp2 args are clamped to >= -126: the bulk of the 67M exps underflow
// (v down to ~-290) and the trans-pipe denormal/underflow slow path is the
// prime suspect for the invariant ~30us across R0/R1/R2.
__global__ __launch_bounds__(1024)
void gm_all(const float* __restrict__ sample,
            const float* __restrict__ mu,
            const float* __restrict__ A,
            const float* __restrict__ w,
            float* __restrict__ out) {
    __shared__ __align__(16) float coef[M*6];     // 24 KiB, pair-interleaved
    __shared__ float partial[16*256];             // 16 KiB

    const int t    = threadIdx.x;
    const int lane = t & 63;
    const int wv   = t >> 6;
    const int base = blockIdx.x * 256;

    // ---- issue all global loads up front ----
    float2 s[4];
    #pragma unroll
    for (int k = 0; k < 4; ++k)
        s[k] = ((const float2*)sample)[base + 64*k + lane];

    const float4 a4  = ((const float4*)A)[t];     // A00,A01,A10,A11 of comp t
    const float2 mu2 = ((const float2*)mu)[t];
    const float  wt  = w[t];

    float4 wq[4];                                 // all 1024 w's, 16/lane
    #pragma unroll
    for (int i = 0; i < 4; ++i)
        wq[i] = ((const float4*)w)[lane + 64*i];

    // ---- per-lane coefs for comp j = t ----
    const float g00 = a4.x*a4.x + a4.y*a4.y;
    const float g01 = a4.x*a4.z + a4.y*a4.w;
    const float g11 = a4.z*a4.z + a4.w*a4.w;
    const float gm0 = g00*mu2.x + g01*mu2.y;
    const float gm1 = g01*mu2.x + g11*mu2.y;
    const float mGm = gm0*mu2.x + gm1*mu2.y;
    const float det = g00*g11 - g01*g01;
    const float t2  = wt*LOG2E + 0.5f*__builtin_amdgcn_logf(det);

    // pair-interleaved: comp j -> pair p=j>>1, sub=j&1, coef c at p*12+2c+sub
    {
        float* c = coef + (t >> 1)*12 + (t & 1);
        c[0]  = t2 - LOG2E * mGm;
        c[2]  = LOG2E * 2.0f * gm0;
        c[4]  = LOG2E * 2.0f * gm1;
        c[6]  = -LOG2E * g00;
        c[8]  = -LOG2E * 2.0f * g01;
        c[10] = -LOG2E * g11;
    }

    // ---- w logsumexp (per-wave redundant; overlaps ds_write latency) ----
    float wmax = wq[0].x;
    #pragma unroll
    for (int i = 0; i < 4; ++i) {
        wmax = fmaxf(wmax, wq[i].x); wmax = fmaxf(wmax, wq[i].y);
        wmax = fmaxf(wmax, wq[i].z); wmax = fmaxf(wmax, wq[i].w);
    }
    wmax = wave_max64(wmax);
    float sw = 0.0f;
    #pragma unroll
    for (int i = 0; i < 4; ++i) {
        sw += __builtin_amdgcn_exp2f((wq[i].x - wmax)*LOG2E);
        sw += __builtin_amdgcn_exp2f((wq[i].y - wmax)*LOG2E);
        sw += __builtin_amdgcn_exp2f((wq[i].z - wmax)*LOG2E);
        sw += __builtin_amdgcn_exp2f((wq[i].w - wmax)*LOG2E);
    }
    sw = wave_sum64(sw);
    const float nlse = -(wmax*LOG2E + __builtin_amdgcn_logf(sw));   // -lse2

    // same-wave DS write -> read ordering; no __syncthreads needed
    asm volatile("s_waitcnt lgkmcnt(0)" ::: "memory");
    __builtin_amdgcn_sched_barrier(0);

    // ---- main loop: 32 pairs x 4 samples, pure VALU + broadcast ds_read ----
    v2f X[4], Y[4];
    #pragma unroll
    for (int k = 0; k < 4; ++k) {
        X[k] = (v2f){s[k].x, s[k].x};
        Y[k] = (v2f){s[k].y, s[k].y};
    }
    v2f acc[4] = {(v2f){0,0},(v2f){0,0},(v2f){0,0},(v2f){0,0}};

    const float4* cw = (const float4*)(coef + wv*64*6);   // wave's 32 pairs
    #pragma unroll 4
    for (int p = 0; p < 32; ++p) {
        const float4 q0 = cw[p*3 + 0];    // c0a c0b c1a c1b
        const float4 q1 = cw[p*3 + 1];    // c2a c2b c3a c3b
        const float4 q2 = cw[p*3 + 2];    // c4a c4b c5a c5b
        const v2f c0 = {q0.x, q0.y}, c1 = {q0.z, q0.w};
        const v2f c2 = {q1.x, q1.y}, c3 = {q1.z, q1.w};
        const v2f c4 = {q2.x, q2.y}, c5 = {q2.z, q2.w};
        #pragma unroll
        for (int k = 0; k < 4; ++k) {
            // q = c0 + x(c1 + c3x + c4y) + y(c2 + c5y): 5 pk_fma
            v2f u  = pkfma(c3, X[k], c1);
            u      = pkfma(c4, Y[k], u);
            v2f t3 = pkfma(c5, Y[k], c2);
            v2f v  = pkfma(u,  X[k], c0);
            v      = pkfma(t3, Y[k], v);
            // clamp: keep exp2 out of the underflow/denormal slow path
            const float ea = __builtin_amdgcn_exp2f(fmaxf(v.x, -126.0f));
            const float eb = __builtin_amdgcn_exp2f(fmaxf(v.y, -126.0f));
            acc[k] += (v2f){ea, eb};
        }
    }

    #pragma unroll
    for (int k = 0; k < 4; ++k)
        partial[wv*256 + 64*k + lane] = acc[k].x + acc[k].y;
    __syncthreads();

    if (t < 256) {
        float ssum = partial[t];
        #pragma unroll
        for (int i = 1; i < 16; ++i) ssum += partial[i*256 + t];
        out[base + t] = LN2 * (nlse + __builtin_amdgcn_logf(ssum));
    }
}

extern "C" void kernel_launch(void* const* d_in, const int* in_sizes, int n_in,
                              void* d_out, int out_size, void* d_ws, size_t ws_size,
                              hipStream_t stream) {
    const float* sample = (const float*)d_in[0];
    const float* mu     = (const float*)d_in[1];
    const float* A      = (const float*)d_in[2];
    const float* w      = (const float*)d_in[3];
    float* out = (float*)d_out;
    (void)in_sizes; (void)n_in; (void)out_size; (void)d_ws; (void)ws_size;

    gm_all<<<256, 1024, 0, stream>>>(sample, mu, A, w, out);
}